// Round 5
// baseline (476.829 us; speedup 1.0000x reference)
//
#include <hip/hip_runtime.h>
#include <math.h>

constexpr int NN    = 100000;  // nodes
constexpr int DIN   = 128;
constexpr int DH    = 16;      // hidden
constexpr int NC    = 40;      // classes
constexpr int NBUCK = 1024;    // dst-range buckets
constexpr int RNG   = 98;      // nodes per bucket: 1024*98 = 100352 >= NN; dstLocal < 128 (7 bits)
constexpr int CHUNK = 8192;    // edges per binscatter workgroup

__device__ __forceinline__ unsigned short f32_to_bf16(float f) {
    unsigned b = __float_as_uint(f);
    return (unsigned short)((b + 0x7FFFu + ((b >> 16) & 1u)) >> 16);
}

// ---------- pass 1: global bucket histogram (LDS-staged) ----------
__global__ void k_hist(const int* __restrict__ dst, int E, int* __restrict__ ghist) {
    __shared__ int lh[NBUCK];
    for (int i = threadIdx.x; i < NBUCK; i += blockDim.x) lh[i] = 0;
    __syncthreads();
    int i  = blockIdx.x * blockDim.x + threadIdx.x;
    int st = gridDim.x * blockDim.x;
    for (; i < E; i += st) atomicAdd(&lh[dst[i] / RNG], 1);
    __syncthreads();
    for (int j = threadIdx.x; j < NBUCK; j += blockDim.x) {
        int v = lh[j];
        if (v) atomicAdd(&ghist[j], v);
    }
}

// ---------- pass 2: exclusive scan of 1024 bucket counts (one WG) ----------
__global__ void k_scan(const int* __restrict__ ghist, int* __restrict__ bbase,
                       int* __restrict__ gcursor) {
    __shared__ int s[NBUCK];
    int t = threadIdx.x;  // 1024 threads
    s[t] = ghist[t];
    __syncthreads();
    for (int o = 1; o < NBUCK; o <<= 1) {
        int v = (t >= o) ? s[t - o] : 0;
        __syncthreads();
        s[t] += v;
        __syncthreads();
    }
    int excl = (t == 0) ? 0 : s[t - 1];
    bbase[t]   = excl;
    gcursor[t] = excl;
    if (t == NBUCK - 1) bbase[NBUCK] = s[t];
}

// ---------- pass 3: scatter edges into bucket-ordered packed array ----------
// packed = (dstLocal << 20) | src  (src < 2^17, dstLocal < 98)
__global__ void k_binscatter(const int* __restrict__ src, const int* __restrict__ dst,
                             int E, int* __restrict__ gcursor,
                             unsigned int* __restrict__ packed) {
    __shared__ int lh[NBUCK];
    long e0 = (long)blockIdx.x * CHUNK;
    long e1 = e0 + CHUNK < (long)E ? e0 + CHUNK : (long)E;
    for (int i = threadIdx.x; i < NBUCK; i += blockDim.x) lh[i] = 0;
    __syncthreads();
    for (long e = e0 + threadIdx.x; e < e1; e += blockDim.x)
        atomicAdd(&lh[dst[e] / RNG], 1);
    __syncthreads();
    for (int i = threadIdx.x; i < NBUCK; i += blockDim.x) {
        int c = lh[i];
        lh[i] = c ? atomicAdd(&gcursor[i], c) : 0;  // claim contiguous slot range
    }
    __syncthreads();
    for (long e = e0 + threadIdx.x; e < e1; e += blockDim.x) {
        int d = dst[e];
        int b = d / RNG;
        int slot = atomicAdd(&lh[b], 1);
        packed[slot] = ((unsigned)(d - b * RNG) << 20) | (unsigned)src[e];
    }
}

// ---------- projection: p1l (bf16 rows) and p1r (f32) ----------
// per-block half: even blocks -> W1l/bf16, odd blocks -> W1r/f32 (weight ptr block-uniform)
__global__ void k_proj(const float* __restrict__ x,
                       const float* __restrict__ W1l, const float* __restrict__ W1r,
                       unsigned short* __restrict__ p1l16, float* __restrict__ p1r) {
    int b = blockIdx.x;
    int n = (b >> 1) * blockDim.x + threadIdx.x;
    if (n >= NN) return;
    const int half  = b & 1;
    const float* W  = half ? W1r : W1l;
    const float* xr = x + (long)n * DIN;
    float acc[DH];
    #pragma unroll
    for (int j = 0; j < DH; ++j) acc[j] = 0.0f;
    for (int k4 = 0; k4 < DIN / 4; ++k4) {
        float4 xv = *(const float4*)(xr + 4 * k4);
        const float* wr = W + 4 * k4 * DH;
        #pragma unroll
        for (int j = 0; j < DH; ++j) {
            acc[j] = fmaf(xv.x, wr[j],          acc[j]);
            acc[j] = fmaf(xv.y, wr[DH + j],     acc[j]);
            acc[j] = fmaf(xv.z, wr[2 * DH + j], acc[j]);
            acc[j] = fmaf(xv.w, wr[3 * DH + j], acc[j]);
        }
    }
    if (half) {
        float4* po = (float4*)(p1r + (long)n * DH);
        po[0] = make_float4(acc[0],  acc[1],  acc[2],  acc[3]);
        po[1] = make_float4(acc[4],  acc[5],  acc[6],  acc[7]);
        po[2] = make_float4(acc[8],  acc[9],  acc[10], acc[11]);
        po[3] = make_float4(acc[12], acc[13], acc[14], acc[15]);
    } else {
        union { unsigned short us[16]; uint4 u4[2]; } pk;
        #pragma unroll
        for (int j = 0; j < DH; ++j) pk.us[j] = f32_to_bf16(acc[j]);
        uint4* po = (uint4*)(p1l16 + (long)n * DH);
        po[0] = pk.u4[0];
        po[1] = pk.u4[1];
    }
}

// ---------- layer-1 aggregate per bucket (LDS accumulation) ----------
__global__ __launch_bounds__(256) void k_agg1(
    const int* __restrict__ bbase, const unsigned int* __restrict__ packed,
    const unsigned short* __restrict__ p1l16, const float* __restrict__ p1r,
    const float* __restrict__ b1,
    float* __restrict__ h, unsigned short* __restrict__ h16)
{
    __shared__ float agg[RNG][DH + 1];   // +1 pad: bank spread
    __shared__ int   ldeg[RNG];
    int b  = blockIdx.x;
    int n0 = b * RNG;
    int nr = NN - n0; if (nr > RNG) nr = RNG;   // may be <= 0 for tail buckets

    for (int i = threadIdx.x; i < RNG * (DH + 1); i += blockDim.x) (&agg[0][0])[i] = 0.0f;
    for (int i = threadIdx.x; i < RNG; i += blockDim.x) ldeg[i] = 0;
    __syncthreads();

    int s0 = bbase[b], s1 = bbase[b + 1];
    for (int t = s0 + threadIdx.x; t < s1; t += blockDim.x) {
        unsigned p = packed[t];
        int srcn = (int)(p & 0xFFFFFu);
        int dl   = (int)(p >> 20);
        const uint4* row = (const uint4*)(p1l16 + (long)srcn * DH);
        uint4 a = row[0], c = row[1];
        atomicAdd(&ldeg[dl], 1);
        float* ar = agg[dl];
        unsigned w[8] = {a.x, a.y, a.z, a.w, c.x, c.y, c.z, c.w};
        #pragma unroll
        for (int j = 0; j < 8; ++j) {
            atomicAdd(&ar[2 * j],     __uint_as_float(w[j] << 16));
            atomicAdd(&ar[2 * j + 1], __uint_as_float(w[j] & 0xFFFF0000u));
        }
    }
    __syncthreads();

    for (int i = threadIdx.x; i < nr * DH; i += blockDim.x) {
        int nl = i >> 4, d = i & 15;
        long n = n0 + nl;
        float inv = 1.0f / fmaxf((float)ldeg[nl], 1.0f);
        float v = fmaf(agg[nl][d], inv, b1[d] + p1r[n * DH + d]);
        v = fmaxf(v, 0.0f);
        h[n * DH + d]   = v;
        h16[n * DH + d] = f32_to_bf16(v);
    }
}

// ---------- layer-2 aggregate + linear + log_softmax per bucket ----------
__global__ __launch_bounds__(256) void k_final(
    const int* __restrict__ bbase, const unsigned int* __restrict__ packed,
    const unsigned short* __restrict__ h16, const float* __restrict__ h,
    const float* __restrict__ W2l, const float* __restrict__ b2,
    const float* __restrict__ W2r, float* __restrict__ out)
{
    __shared__ float agg[RNG][DH + 1];
    __shared__ float hloc[RNG][DH];
    __shared__ int   ldeg[RNG];
    __shared__ float sW[2 * DH * NC + NC];   // W2l | W2r | b2

    for (int i = threadIdx.x; i < DH * NC; i += blockDim.x) {
        sW[i]           = W2l[i];
        sW[DH * NC + i] = W2r[i];
    }
    if (threadIdx.x < NC) sW[2 * DH * NC + threadIdx.x] = b2[threadIdx.x];

    int b  = blockIdx.x;
    int n0 = b * RNG;
    int nr = NN - n0; if (nr > RNG) nr = RNG;

    for (int i = threadIdx.x; i < RNG * (DH + 1); i += blockDim.x) (&agg[0][0])[i] = 0.0f;
    for (int i = threadIdx.x; i < RNG; i += blockDim.x) ldeg[i] = 0;
    for (int i = threadIdx.x; i < nr * DH; i += blockDim.x)
        (&hloc[0][0])[i] = h[(long)n0 * DH + i];
    __syncthreads();

    int s0 = bbase[b], s1 = bbase[b + 1];
    for (int t = s0 + threadIdx.x; t < s1; t += blockDim.x) {
        unsigned p = packed[t];
        int srcn = (int)(p & 0xFFFFFu);
        int dl   = (int)(p >> 20);
        const uint4* row = (const uint4*)(h16 + (long)srcn * DH);
        uint4 a = row[0], c = row[1];
        atomicAdd(&ldeg[dl], 1);
        float* ar = agg[dl];
        unsigned w[8] = {a.x, a.y, a.z, a.w, c.x, c.y, c.z, c.w};
        #pragma unroll
        for (int j = 0; j < 8; ++j) {
            atomicAdd(&ar[2 * j],     __uint_as_float(w[j] << 16));
            atomicAdd(&ar[2 * j + 1], __uint_as_float(w[j] & 0xFFFF0000u));
        }
    }
    __syncthreads();

    int wv = threadIdx.x >> 6, lane = threadIdx.x & 63;
    for (int nl = wv; nl < nr; nl += 4) {
        long n = n0 + nl;
        float inv = 1.0f / fmaxf((float)ldeg[nl], 1.0f);
        int j = (lane < NC) ? lane : 0;
        float o = sW[2 * DH * NC + j];
        #pragma unroll
        for (int k = 0; k < DH; ++k) {
            float ak = agg[nl][k] * inv;   // LDS broadcast
            float hk = hloc[nl][k];        // LDS broadcast
            o = fmaf(ak, sW[k * NC + j],           o);
            o = fmaf(hk, sW[DH * NC + k * NC + j], o);
        }
        float mx = (lane < NC) ? o : -INFINITY;
        #pragma unroll
        for (int m = 32; m; m >>= 1) mx = fmaxf(mx, __shfl_xor(mx, m));
        float ex = (lane < NC) ? __expf(o - mx) : 0.0f;
        float ss = ex;
        #pragma unroll
        for (int m = 32; m; m >>= 1) ss += __shfl_xor(ss, m);
        if (lane < NC) out[n * NC + lane] = o - mx - __logf(ss);
    }
}

// ---------------- launch ----------------

extern "C" void kernel_launch(void* const* d_in, const int* in_sizes, int n_in,
                              void* d_out, int out_size, void* d_ws, size_t ws_size,
                              hipStream_t stream) {
    const float* x   = (const float*)d_in[0];
    const int*   ei  = (const int*)d_in[1];   // [2, E] int32
    const float* W1l = (const float*)d_in[2];
    const float* b1  = (const float*)d_in[3];
    const float* W1r = (const float*)d_in[4];
    const float* W2l = (const float*)d_in[5];
    const float* b2  = (const float*)d_in[6];
    const float* W2r = (const float*)d_in[7];
    float* out = (float*)d_out;

    const int E = in_sizes[1] / 2;
    const int* src = ei;
    const int* dst = ei + E;

    // ws layout (4B words, 16B-aligned sections):
    // ghist[1024] | gcursor[1024] | bbase[1028 pad] | packed[E] | p1r[16N] | h[16N] | p1l16[8N] | h16[8N]
    int* ghist   = (int*)d_ws;
    int* gcursor = ghist + NBUCK;
    int* bbase   = gcursor + NBUCK;
    unsigned int* packed = (unsigned int*)(bbase + NBUCK + 4);
    float* p1r = (float*)(packed + E);
    float* h   = p1r + (long)NN * DH;
    unsigned short* p1l16 = (unsigned short*)(h + (long)NN * DH);
    unsigned short* h16   = p1l16 + (long)NN * DH;

    hipMemsetAsync(ghist, 0, NBUCK * sizeof(int), stream);

    k_hist      <<<512, 256, 0, stream>>>(dst, E, ghist);
    k_scan      <<<1, NBUCK, 0, stream>>>(ghist, bbase, gcursor);
    k_binscatter<<<(E + CHUNK - 1) / CHUNK, 256, 0, stream>>>(src, dst, E, gcursor, packed);
    k_proj      <<<2 * ((NN + 255) / 256), 256, 0, stream>>>(x, W1l, W1r, p1l16, p1r);
    k_agg1      <<<NBUCK, 256, 0, stream>>>(bbase, packed, p1l16, p1r, b1, h, h16);
    k_final     <<<NBUCK, 256, 0, stream>>>(bbase, packed, h16, h, W2l, b2, W2r, out);
}